// Round 2
// baseline (1606.013 us; speedup 1.0000x reference)
//
#include <hip/hip_runtime.h>

#define D_FEAT 64

// 16 threads per edge; each thread loads a float4 of the source row and
// issues 4 fp32 atomics into the aggregation buffer (d_out).
// Per edge: 16 lanes x 16B = 256B coalesced gather.
__global__ void __launch_bounds__(256) gcn_scatter(
        const float* __restrict__ feat,
        const int* __restrict__ src,
        const int* __restrict__ dst,
        float* __restrict__ agg,
        float* __restrict__ deg,
        int nedge) {
    long t = (long)blockIdx.x * blockDim.x + threadIdx.x;
    int e = (int)(t >> 4);        // edge index
    int l = (int)(t & 15);        // quad index within row (l*4 .. l*4+3)
    if (e >= nedge) return;
    int s = src[e];
    int d = dst[e];
    const float4 v = reinterpret_cast<const float4*>(feat + (long)s * D_FEAT)[l];
    float* a = agg + (long)d * D_FEAT + l * 4;
    atomicAdd(a + 0, v.x);
    atomicAdd(a + 1, v.y);
    atomicAdd(a + 2, v.z);
    atomicAdd(a + 3, v.w);
    if (l == 0) atomicAdd(&deg[d], 1.0f);
}

// out = out / deg + in_feat, float4-vectorized. node = i >> 4.
__global__ void __launch_bounds__(256) gcn_finalize(
        const float* __restrict__ in_feat,
        const float* __restrict__ deg,
        float* __restrict__ out,
        int nvec) {
    int i = blockIdx.x * blockDim.x + threadIdx.x;
    if (i >= nvec) return;
    int node = i >> 4;
    float dv = deg[node];
    float4 a = reinterpret_cast<float4*>(out)[i];
    float4 f = reinterpret_cast<const float4*>(in_feat)[i];
    float4 r;
    r.x = a.x / dv + f.x;
    r.y = a.y / dv + f.y;
    r.z = a.z / dv + f.z;
    r.w = a.w / dv + f.w;
    reinterpret_cast<float4*>(out)[i] = r;
}

extern "C" void kernel_launch(void* const* d_in, const int* in_sizes, int n_in,
                              void* d_out, int out_size, void* d_ws, size_t ws_size,
                              hipStream_t stream) {
    const float* in_feat = (const float*)d_in[0];
    const int* src       = (const int*)d_in[1];
    const int* dst       = (const int*)d_in[2];
    float* out = (float*)d_out;
    float* deg = (float*)d_ws;   // N floats of scratch

    int N     = in_sizes[0] / D_FEAT;
    int nedge = in_sizes[1];

    // d_out doubles as the aggregation buffer; it and d_ws are poisoned 0xAA
    // before every timed call — zero them on the capture stream.
    hipMemsetAsync(d_out, 0, (size_t)out_size * sizeof(float), stream);
    hipMemsetAsync(deg, 0, (size_t)N * sizeof(float), stream);

    // Scatter: 16 threads per edge.
    long total_threads = (long)nedge * 16;
    int block = 256;
    int grid = (int)((total_threads + block - 1) / block);
    gcn_scatter<<<grid, block, 0, stream>>>(in_feat, src, dst, out, deg, nedge);

    // Finalize.
    int nvec = N * D_FEAT / 4;
    gcn_finalize<<<(nvec + 255) / 256, 256, 0, stream>>>(in_feat, deg, out, nvec);
}

// Round 3
// 351.593 us; speedup vs baseline: 4.5678x; 4.5678x over previous
//
#include <hip/hip_runtime.h>

#define D_FEAT 64

// ---------- CSR-build + gather path (no fp32 atomics) ----------

// Pass 1: in-degree counts. One edge per thread, int atomics.
__global__ void __launch_bounds__(256) gcn_count(
        const int* __restrict__ dst, int* __restrict__ cnt, int nedge) {
    int e = blockIdx.x * blockDim.x + threadIdx.x;
    if (e >= nedge) return;
    atomicAdd(&cnt[dst[e]], 1);
}

// Pass 2: allocate CSR slot ranges. Order-free (no scan): base[n] comes from
// a global cursor. cur[n] starts at base[n] for pass 3.
__global__ void __launch_bounds__(256) gcn_alloc(
        const int* __restrict__ cnt, int* __restrict__ base,
        int* __restrict__ cur, int* __restrict__ total, int nnode) {
    int n = blockIdx.x * blockDim.x + threadIdx.x;
    if (n >= nnode) return;
    int b = atomicAdd(total, cnt[n]);
    base[n] = b;
    cur[n] = b;
}

// Pass 3: scatter src ids into CSR slots.
__global__ void __launch_bounds__(256) gcn_fill(
        const int* __restrict__ src, const int* __restrict__ dst,
        int* __restrict__ cur, int* __restrict__ csr, int nedge) {
    int e = blockIdx.x * blockDim.x + threadIdx.x;
    if (e >= nedge) return;
    int p = atomicAdd(&cur[dst[e]], 1);
    csr[p] = src[e];
}

// Pass 4: one 64-lane wave per node, lane = feature. Register accumulation,
// 4-deep unroll for outstanding gathers. Single coalesced write per node.
__global__ void __launch_bounds__(256) gcn_aggregate(
        const float* __restrict__ feat, const int* __restrict__ csr,
        const int* __restrict__ base, const int* __restrict__ cnt,
        float* __restrict__ out, int nnode) {
    int node = blockIdx.x * (blockDim.x >> 6) + (threadIdx.x >> 6);
    int lane = threadIdx.x & 63;
    if (node >= nnode) return;
    int b = base[node];
    int c = cnt[node];
    float sum = 0.0f;
    int j = 0;
    for (; j + 4 <= c; j += 4) {
        int s0 = csr[b + j + 0];
        int s1 = csr[b + j + 1];
        int s2 = csr[b + j + 2];
        int s3 = csr[b + j + 3];
        float v0 = feat[(long)s0 * D_FEAT + lane];
        float v1 = feat[(long)s1 * D_FEAT + lane];
        float v2 = feat[(long)s2 * D_FEAT + lane];
        float v3 = feat[(long)s3 * D_FEAT + lane];
        sum += v0 + v1 + v2 + v3;
    }
    for (; j < c; ++j) {
        int s = csr[b + j];
        sum += feat[(long)s * D_FEAT + lane];
    }
    long o = (long)node * D_FEAT + lane;
    out[o] = sum / (float)c + feat[o];
}

// ---------- fallback: direct atomic scatter (round-2 path) ----------

__global__ void __launch_bounds__(256) gcn_scatter(
        const float* __restrict__ feat, const int* __restrict__ src,
        const int* __restrict__ dst, float* __restrict__ agg,
        float* __restrict__ deg, int nedge) {
    long t = (long)blockIdx.x * blockDim.x + threadIdx.x;
    int e = (int)(t >> 4);
    int l = (int)(t & 15);
    if (e >= nedge) return;
    int s = src[e];
    int d = dst[e];
    const float4 v = reinterpret_cast<const float4*>(feat + (long)s * D_FEAT)[l];
    float* a = agg + (long)d * D_FEAT + l * 4;
    atomicAdd(a + 0, v.x);
    atomicAdd(a + 1, v.y);
    atomicAdd(a + 2, v.z);
    atomicAdd(a + 3, v.w);
    if (l == 0) atomicAdd(&deg[d], 1.0f);
}

__global__ void __launch_bounds__(256) gcn_finalize(
        const float* __restrict__ in_feat, const float* __restrict__ deg,
        float* __restrict__ out, int nvec) {
    int i = blockIdx.x * blockDim.x + threadIdx.x;
    if (i >= nvec) return;
    int node = i >> 4;
    float dv = deg[node];
    float4 a = reinterpret_cast<float4*>(out)[i];
    float4 f = reinterpret_cast<const float4*>(in_feat)[i];
    float4 r;
    r.x = a.x / dv + f.x;
    r.y = a.y / dv + f.y;
    r.z = a.z / dv + f.z;
    r.w = a.w / dv + f.w;
    reinterpret_cast<float4*>(out)[i] = r;
}

extern "C" void kernel_launch(void* const* d_in, const int* in_sizes, int n_in,
                              void* d_out, int out_size, void* d_ws, size_t ws_size,
                              hipStream_t stream) {
    const float* in_feat = (const float*)d_in[0];
    const int* src       = (const int*)d_in[1];
    const int* dst       = (const int*)d_in[2];
    float* out = (float*)d_out;

    int N     = in_sizes[0] / D_FEAT;
    int nedge = in_sizes[1];

    // scratch layout (ints): cnt[N] | base[N] | cur[N] | csr[E] | total[1]
    size_t need = ((size_t)3 * N + nedge + 1) * sizeof(int);

    if (ws_size >= need) {
        int* cnt   = (int*)d_ws;
        int* base  = cnt + N;
        int* cur   = base + N;
        int* csr   = cur + N;
        int* total = csr + nedge;

        // cnt and total must be zero each call (ws is re-poisoned to 0xAA).
        hipMemsetAsync(cnt, 0, (size_t)N * sizeof(int), stream);
        hipMemsetAsync(total, 0, sizeof(int), stream);

        int block = 256;
        int egrid = (nedge + block - 1) / block;
        int ngrid = (N + block - 1) / block;

        gcn_count<<<egrid, block, 0, stream>>>(dst, cnt, nedge);
        gcn_alloc<<<ngrid, block, 0, stream>>>(cnt, base, cur, total, N);
        gcn_fill<<<egrid, block, 0, stream>>>(src, dst, cur, csr, nedge);

        int nodes_per_block = block / 64;  // 4
        int agrid = (N + nodes_per_block - 1) / nodes_per_block;
        gcn_aggregate<<<agrid, block, 0, stream>>>(in_feat, csr, base, cnt, out, N);
    } else {
        // fallback: direct atomic path
        float* deg = (float*)d_ws;
        hipMemsetAsync(d_out, 0, (size_t)out_size * sizeof(float), stream);
        hipMemsetAsync(deg, 0, (size_t)N * sizeof(float), stream);
        long total_threads = (long)nedge * 16;
        int block = 256;
        int grid = (int)((total_threads + block - 1) / block);
        gcn_scatter<<<grid, block, 0, stream>>>(in_feat, src, dst, out, deg, nedge);
        int nvec = N * D_FEAT / 4;
        gcn_finalize<<<(nvec + 255) / 256, 256, 0, stream>>>(in_feat, deg, out, nvec);
    }
}

// Round 4
// 331.801 us; speedup vs baseline: 4.8403x; 1.0596x over previous
//
#include <hip/hip_runtime.h>

#define D_FEAT 64

// ---------- linked-list (CSC) build + chase-aggregate path ----------

// One pass: per edge, push e onto dst's list. head[] updates are random 4B
// atomicExch (same atomic count as the old fill pass), but next[] writes are
// indexed by e -> fully coalesced streaming writes (no false-shared lines).
__global__ void __launch_bounds__(256) gcn_build_ll(
        const int* __restrict__ src, const int* __restrict__ dst,
        int* __restrict__ head, int* __restrict__ next, int nedge) {
    int e = blockIdx.x * blockDim.x + threadIdx.x;
    if (e >= nedge) return;
    int d = dst[e];
    int old = atomicExch(&head[d], e);
    next[e] = old;
}

// One 64-lane wave per 4 nodes: 4 independent list chases interleaved for
// 4x MLP on the dependent next[e] loads. lane = feature index. Degree is
// counted during the walk (self-loops guarantee c >= 1).
__global__ void __launch_bounds__(256) gcn_aggregate_ll(
        const float* __restrict__ feat, const int* __restrict__ head,
        const int* __restrict__ next, const int* __restrict__ src,
        float* __restrict__ out, int nnode) {
    int w = blockIdx.x * (blockDim.x >> 6) + (threadIdx.x >> 6);
    int lane = threadIdx.x & 63;
    int n0 = w * 4;
    if (n0 >= nnode) return;

    int e0 = head[n0];
    int e1 = (n0 + 1 < nnode) ? head[n0 + 1] : -1;
    int e2 = (n0 + 2 < nnode) ? head[n0 + 2] : -1;
    int e3 = (n0 + 3 < nnode) ? head[n0 + 3] : -1;

    float s0 = 0.f, s1 = 0.f, s2 = 0.f, s3 = 0.f;
    int c0 = 0, c1 = 0, c2 = 0, c3 = 0;

    // AND == -1 iff all chains exhausted (non-negative values have bit31=0).
    while ((e0 & e1 & e2 & e3) != -1) {
        if (e0 != -1) {
            int sx = src[e0];
            int nx = next[e0];
            s0 += feat[(long)sx * D_FEAT + lane];
            e0 = nx; c0++;
        }
        if (e1 != -1) {
            int sx = src[e1];
            int nx = next[e1];
            s1 += feat[(long)sx * D_FEAT + lane];
            e1 = nx; c1++;
        }
        if (e2 != -1) {
            int sx = src[e2];
            int nx = next[e2];
            s2 += feat[(long)sx * D_FEAT + lane];
            e2 = nx; c2++;
        }
        if (e3 != -1) {
            int sx = src[e3];
            int nx = next[e3];
            s3 += feat[(long)sx * D_FEAT + lane];
            e3 = nx; c3++;
        }
    }

    long o0 = (long)n0 * D_FEAT + lane;
    out[o0] = s0 / (float)c0 + feat[o0];
    if (n0 + 1 < nnode) { long o = o0 + D_FEAT;     out[o] = s1 / (float)c1 + feat[o]; }
    if (n0 + 2 < nnode) { long o = o0 + 2 * D_FEAT; out[o] = s2 / (float)c2 + feat[o]; }
    if (n0 + 3 < nnode) { long o = o0 + 3 * D_FEAT; out[o] = s3 / (float)c3 + feat[o]; }
}

// ---------- fallback: direct atomic scatter ----------

__global__ void __launch_bounds__(256) gcn_scatter(
        const float* __restrict__ feat, const int* __restrict__ src,
        const int* __restrict__ dst, float* __restrict__ agg,
        float* __restrict__ deg, int nedge) {
    long t = (long)blockIdx.x * blockDim.x + threadIdx.x;
    int e = (int)(t >> 4);
    int l = (int)(t & 15);
    if (e >= nedge) return;
    int s = src[e];
    int d = dst[e];
    const float4 v = reinterpret_cast<const float4*>(feat + (long)s * D_FEAT)[l];
    float* a = agg + (long)d * D_FEAT + l * 4;
    atomicAdd(a + 0, v.x);
    atomicAdd(a + 1, v.y);
    atomicAdd(a + 2, v.z);
    atomicAdd(a + 3, v.w);
    if (l == 0) atomicAdd(&deg[d], 1.0f);
}

__global__ void __launch_bounds__(256) gcn_finalize(
        const float* __restrict__ in_feat, const float* __restrict__ deg,
        float* __restrict__ out, int nvec) {
    int i = blockIdx.x * blockDim.x + threadIdx.x;
    if (i >= nvec) return;
    int node = i >> 4;
    float dv = deg[node];
    float4 a = reinterpret_cast<float4*>(out)[i];
    float4 f = reinterpret_cast<const float4*>(in_feat)[i];
    float4 r;
    r.x = a.x / dv + f.x;
    r.y = a.y / dv + f.y;
    r.z = a.z / dv + f.z;
    r.w = a.w / dv + f.w;
    reinterpret_cast<float4*>(out)[i] = r;
}

extern "C" void kernel_launch(void* const* d_in, const int* in_sizes, int n_in,
                              void* d_out, int out_size, void* d_ws, size_t ws_size,
                              hipStream_t stream) {
    const float* in_feat = (const float*)d_in[0];
    const int* src       = (const int*)d_in[1];
    const int* dst       = (const int*)d_in[2];
    float* out = (float*)d_out;

    int N     = in_sizes[0] / D_FEAT;
    int nedge = in_sizes[1];

    // scratch layout (ints): head[N] | next[E]
    size_t need = ((size_t)N + (size_t)nedge) * sizeof(int);

    if (ws_size >= need) {
        int* head = (int*)d_ws;
        int* next = head + N;

        // head must be -1 each call (ws re-poisoned to 0xAA); 0xFF bytes = -1.
        hipMemsetAsync(head, 0xFF, (size_t)N * sizeof(int), stream);

        int block = 256;
        int egrid = (nedge + block - 1) / block;
        gcn_build_ll<<<egrid, block, 0, stream>>>(src, dst, head, next, nedge);

        int nodes_per_block = (block / 64) * 4;  // 16
        int agrid = (N + nodes_per_block - 1) / nodes_per_block;
        gcn_aggregate_ll<<<agrid, block, 0, stream>>>(in_feat, head, next, src, out, N);
    } else {
        // fallback: direct atomic path
        float* deg = (float*)d_ws;
        hipMemsetAsync(d_out, 0, (size_t)out_size * sizeof(float), stream);
        hipMemsetAsync(deg, 0, (size_t)N * sizeof(float), stream);
        long total_threads = (long)nedge * 16;
        int block = 256;
        int grid = (int)((total_threads + block - 1) / block);
        gcn_scatter<<<grid, block, 0, stream>>>(in_feat, src, dst, out, deg, nedge);
        int nvec = N * D_FEAT / 4;
        gcn_finalize<<<(nvec + 255) / 256, 256, 0, stream>>>(in_feat, deg, out, nvec);
    }
}